// Round 15
// baseline (308.247 us; speedup 1.0000x reference)
//
#include <hip/hip_runtime.h>
#include <hip/hip_bf16.h>

typedef __bf16 bf16;
typedef float f32x4 __attribute__((ext_vector_type(4)));
typedef float f32x16 __attribute__((ext_vector_type(16)));
typedef bf16 bf16x8 __attribute__((ext_vector_type(8)));
typedef bf16 bf16x2 __attribute__((ext_vector_type(2)));
typedef unsigned u32x4 __attribute__((ext_vector_type(4)));

#define MFMA16(a,b,c) __builtin_amdgcn_mfma_f32_16x16x32_bf16((a),(b),(c),0,0,0)
#define MFMA32(a,b,c) __builtin_amdgcn_mfma_f32_32x32x16_bf16((a),(b),(c),0,0,0)

__device__ __forceinline__ void gload16(const void* g, void* l) {
    __builtin_amdgcn_global_load_lds((const __attribute__((address_space(1))) unsigned*)g,
                                     (__attribute__((address_space(3))) unsigned*)l, 16, 0, 0);
}

__device__ __forceinline__ unsigned pk(float lo, float hi) {
    bf16x2 t; t[0] = (bf16)lo; t[1] = (bf16)hi;
    return __builtin_bit_cast(unsigned, t);
}

// ---------------------------------------------------------------------------
// f32 -> bf16 converters. Weights land CONTIGUOUSLY in Wqkv[6144][4096].
// Exact 1D grid: 16384 blocks, no idle blocks, no bounds checks.
// ---------------------------------------------------------------------------
__device__ __forceinline__ void cvt8(const float* __restrict__ in, bf16* __restrict__ out, int i) {
    const float4* p = (const float4*)in + (size_t)i * 2;
    float4 a = p[0], b = p[1];
    bf16x8 o;
    o[0]=(bf16)a.x; o[1]=(bf16)a.y; o[2]=(bf16)a.z; o[3]=(bf16)a.w;
    o[4]=(bf16)b.x; o[5]=(bf16)b.y; o[6]=(bf16)b.z; o[7]=(bf16)b.w;
    *((bf16x8*)out + i) = o;
}

__global__ __launch_bounds__(256) void cvt_all(const float* __restrict__ x, const float* __restrict__ wq,
                                               const float* __restrict__ wk, const float* __restrict__ wv,
                                               bf16* __restrict__ xb, bf16* __restrict__ wqkv) {
    int b = blockIdx.x;
    const float* src; bf16* dst; int i;
    if (b < 4096)       { src = x;  dst = xb;                i = b * 256 + threadIdx.x; }            // 1048576
    else if (b < 12288) { src = wq; dst = wqkv;              i = (b - 4096) * 256 + threadIdx.x; }   // 2097152
    else if (b < 14336) { src = wk; dst = wqkv + 16777216;   i = (b - 12288) * 256 + threadIdx.x; }  // 524288
    else                { src = wv; dst = wqkv + 20971520;   i = (b - 14336) * 256 + threadIdx.x; }  // 524288
    cvt8(src, dst, i);
}

// ---------------------------------------------------------------------------
// QKV GEMM (R14 best): 128x192 tile -> 512 blocks = 2 blocks/CU. 4 waves,
// per-wave 128x48. 2-deep counted-vmcnt pipeline, vmcnt(10). LDS 80 KB.
// Q columns scaled by qscale*log2(e) (flash softmax runs in exp2 domain).
// ---------------------------------------------------------------------------
__device__ __forceinline__ void stage_tile_qkv(const bf16* __restrict__ A, const bf16* __restrict__ B,
                                               int K, int bm, int bn, int k0,
                                               bf16* As, bf16* Bs, int tid) {
#pragma unroll
    for (int i=0;i<4;++i) {                       // A: 128 rows x 128B = 16 KB
        int off = i*4096 + tid*16;
        int row = off >> 7;
        int cg  = (tid & 7) ^ (row & 7);
        gload16(A + (size_t)(bm+row)*K + k0 + cg*8, (char*)As + off);
    }
#pragma unroll
    for (int i=0;i<6;++i) {                       // B: 192 rows x 128B = 24 KB
        int off = i*4096 + tid*16;
        int row = off >> 7;
        int cg  = (tid & 7) ^ (row & 7);
        gload16(B + (size_t)(bn+row)*K + k0 + cg*8, (char*)Bs + off);
    }
}

__global__ __launch_bounds__(256) void gemm_qkv(const bf16* __restrict__ A, const bf16* __restrict__ W,
                                                bf16* __restrict__ C, float qscale) {
    __shared__ __align__(16) bf16 As[2*8192];     // 2 x 16 KB
    __shared__ __align__(16) bf16 Bs[2*12288];    // 2 x 24 KB
    const int tid = threadIdx.x, lane = tid & 63, wn = tid >> 6;   // 4 waves, wave = n-quarter
    const int lr = lane & 15, ls = lane >> 4;

    // grid (16, 32) = 512 blocks; XCD-bijective chunking (chunk = 64)
    int flat = blockIdx.y * 16 + blockIdx.x;
    int id = (flat & 7) * 64 + (flat >> 3);
    const int bm = (id & 15) * 128, bn = (id >> 4) * 192;
    const int K = 4096, nt = 64;

    f32x4 acc[8][3];
#pragma unroll
    for (int mm=0;mm<8;++mm)
#pragma unroll
        for (int nn=0;nn<3;++nn)
#pragma unroll
            for (int r=0;r<4;++r) acc[mm][nn][r] = 0.f;

    stage_tile_qkv(A, W, K, bm, bn, 0,  As,        Bs,         tid);
    stage_tile_qkv(A, W, K, bm, bn, 64, As + 8192, Bs + 12288, tid);

    for (int t = 0; t < nt; ++t) {
        const int cur = t & 1;
        bf16* AsC = As + cur * 8192;
        bf16* BsC = Bs + cur * 12288;

        if (t < nt - 1) asm volatile("s_waitcnt vmcnt(10)" ::: "memory");
        else            asm volatile("s_waitcnt vmcnt(0)" ::: "memory");
        __builtin_amdgcn_s_barrier();
        __builtin_amdgcn_sched_barrier(0);

        // ---- ks = 0 ----
        bf16x8 af0[8], bf0[3];
#pragma unroll
        for (int mm=0;mm<8;++mm) {
            int row = mm*16 + lr;
            af0[mm] = *(const bf16x8*)((char*)AsC + row*128 + ((ls ^ (row&7))<<4));
        }
#pragma unroll
        for (int nn=0;nn<3;++nn) {
            int row = wn*48 + nn*16 + lr;
            bf0[nn] = *(const bf16x8*)((char*)BsC + row*128 + ((ls ^ (row&7))<<4));
        }
        asm volatile("s_waitcnt lgkmcnt(0)" ::: "memory");
        __builtin_amdgcn_sched_barrier(0);
        __builtin_amdgcn_s_setprio(1);
#pragma unroll
        for (int mm=0;mm<8;++mm)
#pragma unroll
            for (int nn=0;nn<3;++nn) acc[mm][nn] = MFMA16(af0[mm], bf0[nn], acc[mm][nn]);
        __builtin_amdgcn_s_setprio(0);

        // ---- ks = 1 ----
        bf16x8 af1[8], bf1[3];
#pragma unroll
        for (int mm=0;mm<8;++mm) {
            int row = mm*16 + lr;
            af1[mm] = *(const bf16x8*)((char*)AsC + row*128 + (((4+ls) ^ (row&7))<<4));
        }
#pragma unroll
        for (int nn=0;nn<3;++nn) {
            int row = wn*48 + nn*16 + lr;
            bf1[nn] = *(const bf16x8*)((char*)BsC + row*128 + (((4+ls) ^ (row&7))<<4));
        }
        asm volatile("s_waitcnt lgkmcnt(0)" ::: "memory");
        __builtin_amdgcn_sched_barrier(0);
        __builtin_amdgcn_s_barrier();           // every wave done reading buf[cur]
        __builtin_amdgcn_sched_barrier(0);

        if (t + 2 < nt)
            stage_tile_qkv(A, W, K, bm, bn, (t+2) << 6, AsC, BsC, tid);

        __builtin_amdgcn_s_setprio(1);
#pragma unroll
        for (int mm=0;mm<8;++mm)
#pragma unroll
            for (int nn=0;nn<3;++nn) acc[mm][nn] = MFMA16(af1[mm], bf1[nn], acc[mm][nn]);
        __builtin_amdgcn_s_setprio(0);
    }

#pragma unroll
    for (int mm=0;mm<8;++mm)
#pragma unroll
        for (int nn=0;nn<3;++nn) {
            int ng = bn + wn*48 + nn*16 + lr;
            float s = (ng < 4096) ? qscale : 1.0f;
#pragma unroll
            for (int r=0;r<4;++r) {
                int mg = bm + mm*16 + ls*4 + r;
                C[(size_t)mg * 6144 + ng] = (bf16)(acc[mm][nn][r] * s);
            }
        }
}

// ---------------------------------------------------------------------------
// O-projection GEMM: proven R8 128^2 2-deep counted-vmcnt structure.
// ---------------------------------------------------------------------------
__device__ __forceinline__ void stage_tile(const bf16* __restrict__ A, const bf16* __restrict__ B,
                                           int K, int bm, int bn, int k0,
                                           bf16* As, bf16* Bs, int wv, int lane) {
#pragma unroll
    for (int i=0;i<4;++i) {
        int off = i*4096 + wv*1024 + lane*16;
        int row = off >> 7;
        int cg = (lane & 7) ^ (row & 7);
        gload16(A + (size_t)(bm+row)*K + k0 + cg*8, (char*)As + off);
    }
#pragma unroll
    for (int i=0;i<4;++i) {
        int off = i*4096 + wv*1024 + lane*16;
        int row = off >> 7;
        int cg = (lane & 7) ^ (row & 7);
        gload16(B + (size_t)(bn+row)*K + k0 + cg*8, (char*)Bs + off);
    }
}

__device__ __forceinline__ void gemm_core(const bf16* __restrict__ A, const bf16* __restrict__ B,
                                          int K, int bm, int bn, bf16* As, bf16* Bs, f32x4 (&acc)[4][4]) {
    const int tid = threadIdx.x, lane = tid & 63, wv = tid >> 6;
    const int wr = wv >> 1, wc = wv & 1, lr = lane & 15, ls = lane >> 4;

#pragma unroll
    for (int mm=0;mm<4;++mm)
#pragma unroll
        for (int nn=0;nn<4;++nn)
#pragma unroll
            for (int r=0;r<4;++r) acc[mm][nn][r] = 0.f;

    const int nt = K >> 6;
    stage_tile(A, B, K, bm, bn, 0,  As,        Bs,        wv, lane);
    stage_tile(A, B, K, bm, bn, 64, As + 8192, Bs + 8192, wv, lane);

    for (int t = 0; t < nt; ++t) {
        const int cur = t & 1;
        bf16* AsC = As + cur * 8192;
        bf16* BsC = Bs + cur * 8192;

        if (t < nt - 1) asm volatile("s_waitcnt vmcnt(8)" ::: "memory");
        else            asm volatile("s_waitcnt vmcnt(0)" ::: "memory");
        __builtin_amdgcn_s_barrier();
        __builtin_amdgcn_sched_barrier(0);

        bf16x8 af[2][4], bfr[2][4];
#pragma unroll
        for (int ks=0; ks<2; ++ks) {
#pragma unroll
            for (int mm=0;mm<4;++mm) {
                int row = wr*64 + mm*16 + lr;
                af[ks][mm] = *(const bf16x8*)((char*)AsC + row*128 + (((ks*4+ls) ^ (row&7))<<4));
            }
#pragma unroll
            for (int nn=0;nn<4;++nn) {
                int row = wc*64 + nn*16 + lr;
                bfr[ks][nn] = *(const bf16x8*)((char*)BsC + row*128 + (((ks*4+ls) ^ (row&7))<<4));
            }
        }
        asm volatile("s_waitcnt lgkmcnt(0)" ::: "memory");
        __builtin_amdgcn_sched_barrier(0);
        __builtin_amdgcn_s_barrier();
        __builtin_amdgcn_sched_barrier(0);

        if (t + 2 < nt)
            stage_tile(A, B, K, bm, bn, (t+2) << 6, AsC, BsC, wv, lane);

        __builtin_amdgcn_s_setprio(1);
#pragma unroll
        for (int ks=0; ks<2; ++ks)
#pragma unroll
            for (int mm=0;mm<4;++mm)
#pragma unroll
                for (int nn=0;nn<4;++nn)
                    acc[mm][nn] = MFMA16(af[ks][mm], bfr[ks][nn], acc[mm][nn]);
        __builtin_amdgcn_s_setprio(0);
    }
}

__global__ __launch_bounds__(256) void gemm_o(const bf16* __restrict__ A, const bf16* __restrict__ B,
                                              float* __restrict__ Cp) {
    __shared__ __align__(16) bf16 As[2*128*64];
    __shared__ __align__(16) bf16 Bs[2*128*64];
    int flat = blockIdx.y * gridDim.x + blockIdx.x;
    int id = (flat & 7) * 64 + (flat >> 3);           // 512 = 8 * 64
    int bm = (id & 15) * 128, bn = (id >> 4) * 128;
    f32x4 acc[4][4];
    gemm_core(A, B, 4096, bm, bn, As, Bs, acc);

    const int lane = threadIdx.x & 63, wv = threadIdx.x >> 6;
    const int wr = wv >> 1, wc = wv & 1, lr = lane & 15, ls = lane >> 4;
#pragma unroll
    for (int mm=0;mm<4;++mm)
#pragma unroll
        for (int nn=0;nn<4;++nn)
#pragma unroll
            for (int r=0;r<4;++r) {
                int mg = bm + wr*64 + mm*16 + ls*4 + r;
                int ng = bn + wc*64 + nn*16 + lr;
                Cp[(size_t)mg * 4096 + ng] = acc[mm][nn][r];
            }
}

// ---------------------------------------------------------------------------
// Vt transpose (64x64 LDS tiles) + f32 cache emission + Wo bf16 conversion.
// ---------------------------------------------------------------------------
__global__ __launch_bounds__(256) void trans_cache_cvt(const bf16* __restrict__ QKVb, bf16* __restrict__ Vt,
                                                       float* __restrict__ cacheK, float* __restrict__ cacheV,
                                                       const float* __restrict__ Wo, bf16* __restrict__ Wob) {
    int b = blockIdx.x;
    if (b < 512) {
        __shared__ bf16 t[64][70];
        int dt = b & 15, st = b >> 4;
        int tt = threadIdx.x;
        int r = tt >> 2, c0 = (tt & 3) * 16;
#pragma unroll
        for (int i = 0; i < 2; ++i) {
            bf16x8 v = *(const bf16x8*)(QKVb + (size_t)(st*64 + r)*6144 + 5120 + dt*64 + c0 + i*8);
#pragma unroll
            for (int j = 0; j < 8; ++j) t[c0 + i*8 + j][r] = v[j];
        }
        __syncthreads();
        int c = tt >> 2, r0 = (tt & 3) * 16;
#pragma unroll
        for (int i = 0; i < 2; ++i) {
            bf16x8 v = *(const bf16x8*)(&t[c][r0 + i*8]);
            *(bf16x8*)(Vt + (size_t)(dt*64 + c)*2048 + st*64 + r0 + i*8) = v;
        }
    } else if (b < 2560) {
        int g = (b - 512) * 256 + threadIdx.x;
        int d8 = g & 15, s = (g >> 4) & 2047, j = (g >> 15) & 7, kv = g >> 18;
        int hk = j >> 2;
        bf16x8 v = *(const bf16x8*)(QKVb + (size_t)s*6144 + 4096 + kv*1024 + hk*128 + d8*8);
        float* dst = (kv ? cacheV : cacheK) + ((size_t)j*2048 + s)*128 + d8*8;
        float4 lo, hi;
        lo.x=(float)v[0]; lo.y=(float)v[1]; lo.z=(float)v[2]; lo.w=(float)v[3];
        hi.x=(float)v[4]; hi.y=(float)v[5]; hi.z=(float)v[6]; hi.w=(float)v[7];
        *(float4*)dst = lo;
        *(float4*)(dst + 4) = hi;
    } else {
        int i = (b - 2560) * 256 + threadIdx.x;
        if (i < 2097152) cvt8(Wo, Wob, i);
    }
}

// ---------------------------------------------------------------------------
// Flash attention (R13 structure): KVBLK=128, 16 iterations, 4 independent
// QK chains, setprio MFMA clusters, 128 KB double-buffered LDS.
// Softmax in exp2 domain (log2e folded into Q-scale upstream): exp2f = raw
// v_exp_f32 (one less VALU mul per exp); defer-max threshold 8*log2e.
// ---------------------------------------------------------------------------
__device__ __forceinline__ void stage_kv(const bf16* __restrict__ QKVb, const bf16* __restrict__ Vt,
                                         char* Ks, char* Vs, int kvh, int kt, int buf,
                                         int tid) {
#pragma unroll
    for (int i=0;i<4;++i) {                       // K tile [128 s][128 d] bf16, 32KB
        int off = i*8192 + tid*16;
        int row = off >> 8;
        int cg = (tid & 15) ^ (row & 7);
        gload16(QKVb + (size_t)(kt*128+row)*6144 + 4096 + kvh*128 + cg*8, Ks + buf*32768 + off);
    }
#pragma unroll
    for (int i=0;i<4;++i) {                       // V tile [128 d][128 s] bf16, 32KB
        int off = i*8192 + tid*16;
        int d = off >> 8;
        int cg = (tid & 15) ^ (d & 7);
        gload16(Vt + (size_t)(kvh*128+d)*2048 + kt*128 + cg*8, Vs + buf*32768 + off);
    }
}

__global__ __launch_bounds__(512) void flash_attn(const bf16* __restrict__ QKVb, const bf16* __restrict__ Vt,
                                                  bf16* __restrict__ AO) {
    __shared__ __align__(16) char Ks[2*32768];
    __shared__ __align__(16) char Vs[2*32768];
    const int tid = threadIdx.x, lane = tid & 63, wq = tid >> 6;
    const int l31 = lane & 31, hi = lane >> 5;
    const int h = blockIdx.y, kvh = h >> 2;
    const int q0w = blockIdx.x * 256 + wq * 32;

    bf16x8 qf[8];
#pragma unroll
    for (int f=0; f<8; ++f)
        qf[f] = *(const bf16x8*)(QKVb + (size_t)(q0w + l31)*6144 + h*128 + f*16 + hi*8);

    f32x16 acc[4];
#pragma unroll
    for (int db=0;db<4;++db)
#pragma unroll
        for (int r=0;r<16;++r) acc[db][r] = 0.f;
    float mrun = -1e30f, lrun = 0.f;

    stage_kv(QKVb, Vt, Ks, Vs, kvh, 0, 0, tid);
    __syncthreads();

    for (int t = 0; t < 16; ++t) {
        const int cur = t & 1;
        if (t + 1 < 16) stage_kv(QKVb, Vt, Ks, Vs, kvh, t+1, cur^1, tid);

        const char* KsB = Ks + cur*32768;
        f32x16 sc[4];
#pragma unroll
        for (int kc=0;kc<4;++kc)
#pragma unroll
            for (int r=0;r<16;++r) sc[kc][r] = 0.f;
        __builtin_amdgcn_s_setprio(1);
#pragma unroll
        for (int f=0; f<8; ++f) {
#pragma unroll
            for (int kc=0;kc<4;++kc) {
                int row = kc*32 + l31;
                bf16x8 kf = *(const bf16x8*)(KsB + row*256 + (((f*2+hi) ^ (row&7))<<4));
                sc[kc] = MFMA32(kf, qf[f], sc[kc]);
            }
        }
        __builtin_amdgcn_s_setprio(0);

        // online softmax in exp2 domain (scores already scaled by log2e)
        float tmax = sc[0][0];
#pragma unroll
        for (int kc=0;kc<4;++kc)
#pragma unroll
            for (int r=0;r<16;++r) tmax = fmaxf(tmax, sc[kc][r]);
        tmax = fmaxf(tmax, __shfl_xor(tmax, 32, 64));
        if (!__all(tmax <= mrun + 11.5415605f)) {     // = 8 * log2(e): P <= e^8
            float mnew = fmaxf(mrun, tmax);
            float corr = exp2f(mrun - mnew);
            mrun = mnew;
            lrun *= corr;
#pragma unroll
            for (int r=0;r<16;++r) {
                float cr = __shfl(corr, (r&3) + 8*(r>>2) + 4*hi, 64);
#pragma unroll
                for (int db=0;db<4;++db) acc[db][r] *= cr;
            }
        }
        float rs = 0.f;
#pragma unroll
        for (int kc=0;kc<4;++kc)
#pragma unroll
            for (int r=0;r<16;++r) { float e = exp2f(sc[kc][r] - mrun); sc[kc][r] = e; rs += e; }
        rs += __shfl_xor(rs, 32, 64);
        lrun += rs;

        const char* VsB = Vs + cur*32768;
        __builtin_amdgcn_s_setprio(1);
#pragma unroll
        for (int kb=0;kb<8;++kb) {
            const int kc = kb>>1, r0 = (kb&1)*8;
            unsigned a0 = pk(sc[kc][r0+0], sc[kc][r0+1]);
            unsigned a1 = pk(sc[kc][r0+2], sc[kc][r0+3]);
            unsigned b0 = pk(sc[kc][r0+4], sc[kc][r0+5]);
            unsigned b1 = pk(sc[kc][r0+6], sc[kc][r0+7]);
            unsigned sa0 = (unsigned)__shfl_xor((int)a0, 32, 64);
            unsigned sa1 = (unsigned)__shfl_xor((int)a1, 32, 64);
            unsigned sb0 = (unsigned)__shfl_xor((int)b0, 32, 64);
            unsigned sb1 = (unsigned)__shfl_xor((int)b1, 32, 64);
            u32x4 w;
            w[0] = hi ? sb0 : a0;
            w[1] = hi ? sb1 : a1;
            w[2] = hi ? b0 : sa0;
            w[3] = hi ? b1 : sa1;
            bf16x8 pa = __builtin_bit_cast(bf16x8, w);
#pragma unroll
            for (int db=0;db<4;++db) {
                const int d = db*32 + l31;
                bf16x8 vf = *(const bf16x8*)(VsB + d*256 + (((kb*2+hi) ^ (d&7))<<4));
                acc[db] = MFMA32(pa, vf, acc[db]);
            }
        }
        __builtin_amdgcn_s_setprio(0);
        __syncthreads();
    }

    float linv = 1.0f / lrun;
#pragma unroll
    for (int r=0;r<16;++r) {
        int crw = (r&3) + 8*(r>>2) + 4*hi;
        float lv = __shfl(linv, crw, 64);
        size_t qrow = (size_t)q0w + crw;
#pragma unroll
        for (int db=0;db<4;++db)
            AO[qrow*4096 + h*128 + db*32 + l31] = (bf16)(acc[db][r] * lv);
    }
}

extern "C" void kernel_launch(void* const* d_in, const int* in_sizes, int n_in,
                              void* d_out, int out_size, void* d_ws, size_t ws_size,
                              hipStream_t stream) {
    const float* x  = (const float*)d_in[0];
    const float* Wq = (const float*)d_in[1];
    const float* Wk = (const float*)d_in[2];
    const float* Wv = (const float*)d_in[3];
    const float* Wo = (const float*)d_in[4];

    // ws layout (92.3 MB total, phase-disjoint aliasing):
    bf16* xb   = (bf16*)d_ws;                  // [2048,4096]; after gemm_qkv: first 2M elems = Vt
    bf16* QKVb = xb + (size_t)8388608;         // [2048,6144]
    bf16* Wqkv = QKVb + (size_t)12582912;      // [6144,4096]; after gemm_qkv:
                                               //   [0 : 16777216)  = Wo bf16
                                               //   [16777216 : end) = AO [2048,4096]
    bf16* Vt  = xb;
    bf16* Wob = Wqkv;
    bf16* AO  = Wqkv + (size_t)16777216;

    float* out = (float*)d_out;
    float* cacheK = out + (size_t)8388608;
    float* cacheV = cacheK + (size_t)2097152;

    // 1/sqrt(128) * log2(e): flash softmax runs in exp2 domain
    const float qscale = 0.08838834764831845f * 1.4426950408889634f;

    cvt_all<<<16384, 256, 0, stream>>>(x, Wq, Wk, Wv, xb, Wqkv);
    gemm_qkv<<<dim3(16, 32), 256, 0, stream>>>(xb, Wqkv, QKVb, qscale);
    trans_cache_cvt<<<10752, 256, 0, stream>>>(QKVb, Vt, cacheK, cacheV, Wo, Wob);
    flash_attn<<<dim3(8, 32), 512, 0, stream>>>(QKVb, Vt, AO);
    gemm_o<<<dim3(16, 32), 256, 0, stream>>>(AO, Wob, out);
}

// Round 16
// 297.240 us; speedup vs baseline: 1.0370x; 1.0370x over previous
//
#include <hip/hip_runtime.h>
#include <hip/hip_bf16.h>

typedef __bf16 bf16;
typedef float f32x4 __attribute__((ext_vector_type(4)));
typedef float f32x16 __attribute__((ext_vector_type(16)));
typedef bf16 bf16x8 __attribute__((ext_vector_type(8)));
typedef bf16 bf16x2 __attribute__((ext_vector_type(2)));
typedef unsigned u32x4 __attribute__((ext_vector_type(4)));

#define MFMA16(a,b,c) __builtin_amdgcn_mfma_f32_16x16x32_bf16((a),(b),(c),0,0,0)
#define MFMA32(a,b,c) __builtin_amdgcn_mfma_f32_32x32x16_bf16((a),(b),(c),0,0,0)

__device__ __forceinline__ void gload16(const void* g, void* l) {
    __builtin_amdgcn_global_load_lds((const __attribute__((address_space(1))) unsigned*)g,
                                     (__attribute__((address_space(3))) unsigned*)l, 16, 0, 0);
}

__device__ __forceinline__ unsigned pk(float lo, float hi) {
    bf16x2 t; t[0] = (bf16)lo; t[1] = (bf16)hi;
    return __builtin_bit_cast(unsigned, t);
}

// ---------------------------------------------------------------------------
// f32 -> bf16 converters. Weights land CONTIGUOUSLY in Wqkv[6144][4096].
// Exact 1D grid: 16384 blocks, no idle blocks, no bounds checks.
// ---------------------------------------------------------------------------
__device__ __forceinline__ void cvt8(const float* __restrict__ in, bf16* __restrict__ out, int i) {
    const float4* p = (const float4*)in + (size_t)i * 2;
    float4 a = p[0], b = p[1];
    bf16x8 o;
    o[0]=(bf16)a.x; o[1]=(bf16)a.y; o[2]=(bf16)a.z; o[3]=(bf16)a.w;
    o[4]=(bf16)b.x; o[5]=(bf16)b.y; o[6]=(bf16)b.z; o[7]=(bf16)b.w;
    *((bf16x8*)out + i) = o;
}

__global__ __launch_bounds__(256) void cvt_all(const float* __restrict__ x, const float* __restrict__ wq,
                                               const float* __restrict__ wk, const float* __restrict__ wv,
                                               bf16* __restrict__ xb, bf16* __restrict__ wqkv) {
    int b = blockIdx.x;
    const float* src; bf16* dst; int i;
    if (b < 4096)       { src = x;  dst = xb;                i = b * 256 + threadIdx.x; }            // 1048576
    else if (b < 12288) { src = wq; dst = wqkv;              i = (b - 4096) * 256 + threadIdx.x; }   // 2097152
    else if (b < 14336) { src = wk; dst = wqkv + 16777216;   i = (b - 12288) * 256 + threadIdx.x; }  // 524288
    else                { src = wv; dst = wqkv + 20971520;   i = (b - 14336) * 256 + threadIdx.x; }  // 524288
    cvt8(src, dst, i);
}

// ---------------------------------------------------------------------------
// QKV GEMM (R14 best): 128x192 tile -> 512 blocks = 2 blocks/CU. 4 waves,
// per-wave 128x48. 2-deep counted-vmcnt pipeline, vmcnt(10). LDS 80 KB.
// ---------------------------------------------------------------------------
__device__ __forceinline__ void stage_tile_qkv(const bf16* __restrict__ A, const bf16* __restrict__ B,
                                               int K, int bm, int bn, int k0,
                                               bf16* As, bf16* Bs, int tid) {
#pragma unroll
    for (int i=0;i<4;++i) {                       // A: 128 rows x 128B = 16 KB
        int off = i*4096 + tid*16;
        int row = off >> 7;
        int cg  = (tid & 7) ^ (row & 7);
        gload16(A + (size_t)(bm+row)*K + k0 + cg*8, (char*)As + off);
    }
#pragma unroll
    for (int i=0;i<6;++i) {                       // B: 192 rows x 128B = 24 KB
        int off = i*4096 + tid*16;
        int row = off >> 7;
        int cg  = (tid & 7) ^ (row & 7);
        gload16(B + (size_t)(bn+row)*K + k0 + cg*8, (char*)Bs + off);
    }
}

__global__ __launch_bounds__(256) void gemm_qkv(const bf16* __restrict__ A, const bf16* __restrict__ W,
                                                bf16* __restrict__ C, float qscale) {
    __shared__ __align__(16) bf16 As[2*8192];     // 2 x 16 KB
    __shared__ __align__(16) bf16 Bs[2*12288];    // 2 x 24 KB
    const int tid = threadIdx.x, lane = tid & 63, wn = tid >> 6;   // 4 waves, wave = n-quarter
    const int lr = lane & 15, ls = lane >> 4;

    // grid (16, 32) = 512 blocks; XCD-bijective chunking (chunk = 64)
    int flat = blockIdx.y * 16 + blockIdx.x;
    int id = (flat & 7) * 64 + (flat >> 3);
    const int bm = (id & 15) * 128, bn = (id >> 4) * 192;
    const int K = 4096, nt = 64;

    f32x4 acc[8][3];
#pragma unroll
    for (int mm=0;mm<8;++mm)
#pragma unroll
        for (int nn=0;nn<3;++nn)
#pragma unroll
            for (int r=0;r<4;++r) acc[mm][nn][r] = 0.f;

    stage_tile_qkv(A, W, K, bm, bn, 0,  As,        Bs,         tid);
    stage_tile_qkv(A, W, K, bm, bn, 64, As + 8192, Bs + 12288, tid);

    for (int t = 0; t < nt; ++t) {
        const int cur = t & 1;
        bf16* AsC = As + cur * 8192;
        bf16* BsC = Bs + cur * 12288;

        if (t < nt - 1) asm volatile("s_waitcnt vmcnt(10)" ::: "memory");
        else            asm volatile("s_waitcnt vmcnt(0)" ::: "memory");
        __builtin_amdgcn_s_barrier();
        __builtin_amdgcn_sched_barrier(0);

        // ---- ks = 0 ----
        bf16x8 af0[8], bf0[3];
#pragma unroll
        for (int mm=0;mm<8;++mm) {
            int row = mm*16 + lr;
            af0[mm] = *(const bf16x8*)((char*)AsC + row*128 + ((ls ^ (row&7))<<4));
        }
#pragma unroll
        for (int nn=0;nn<3;++nn) {
            int row = wn*48 + nn*16 + lr;
            bf0[nn] = *(const bf16x8*)((char*)BsC + row*128 + ((ls ^ (row&7))<<4));
        }
        asm volatile("s_waitcnt lgkmcnt(0)" ::: "memory");
        __builtin_amdgcn_sched_barrier(0);
        __builtin_amdgcn_s_setprio(1);
#pragma unroll
        for (int mm=0;mm<8;++mm)
#pragma unroll
            for (int nn=0;nn<3;++nn) acc[mm][nn] = MFMA16(af0[mm], bf0[nn], acc[mm][nn]);
        __builtin_amdgcn_s_setprio(0);

        // ---- ks = 1 ----
        bf16x8 af1[8], bf1[3];
#pragma unroll
        for (int mm=0;mm<8;++mm) {
            int row = mm*16 + lr;
            af1[mm] = *(const bf16x8*)((char*)AsC + row*128 + (((4+ls) ^ (row&7))<<4));
        }
#pragma unroll
        for (int nn=0;nn<3;++nn) {
            int row = wn*48 + nn*16 + lr;
            bf1[nn] = *(const bf16x8*)((char*)BsC + row*128 + (((4+ls) ^ (row&7))<<4));
        }
        asm volatile("s_waitcnt lgkmcnt(0)" ::: "memory");
        __builtin_amdgcn_sched_barrier(0);
        __builtin_amdgcn_s_barrier();           // every wave done reading buf[cur]
        __builtin_amdgcn_sched_barrier(0);

        if (t + 2 < nt)
            stage_tile_qkv(A, W, K, bm, bn, (t+2) << 6, AsC, BsC, tid);

        __builtin_amdgcn_s_setprio(1);
#pragma unroll
        for (int mm=0;mm<8;++mm)
#pragma unroll
            for (int nn=0;nn<3;++nn) acc[mm][nn] = MFMA16(af1[mm], bf1[nn], acc[mm][nn]);
        __builtin_amdgcn_s_setprio(0);
    }

#pragma unroll
    for (int mm=0;mm<8;++mm)
#pragma unroll
        for (int nn=0;nn<3;++nn) {
            int ng = bn + wn*48 + nn*16 + lr;
            float s = (ng < 4096) ? qscale : 1.0f;
#pragma unroll
            for (int r=0;r<4;++r) {
                int mg = bm + mm*16 + ls*4 + r;
                C[(size_t)mg * 6144 + ng] = (bf16)(acc[mm][nn][r] * s);
            }
        }
}

// ---------------------------------------------------------------------------
// O-projection GEMM: proven R8 128^2 2-deep counted-vmcnt structure.
// ---------------------------------------------------------------------------
__device__ __forceinline__ void stage_tile(const bf16* __restrict__ A, const bf16* __restrict__ B,
                                           int K, int bm, int bn, int k0,
                                           bf16* As, bf16* Bs, int wv, int lane) {
#pragma unroll
    for (int i=0;i<4;++i) {
        int off = i*4096 + wv*1024 + lane*16;
        int row = off >> 7;
        int cg = (lane & 7) ^ (row & 7);
        gload16(A + (size_t)(bm+row)*K + k0 + cg*8, (char*)As + off);
    }
#pragma unroll
    for (int i=0;i<4;++i) {
        int off = i*4096 + wv*1024 + lane*16;
        int row = off >> 7;
        int cg = (lane & 7) ^ (row & 7);
        gload16(B + (size_t)(bn+row)*K + k0 + cg*8, (char*)Bs + off);
    }
}

__device__ __forceinline__ void gemm_core(const bf16* __restrict__ A, const bf16* __restrict__ B,
                                          int K, int bm, int bn, bf16* As, bf16* Bs, f32x4 (&acc)[4][4]) {
    const int tid = threadIdx.x, lane = tid & 63, wv = tid >> 6;
    const int wr = wv >> 1, wc = wv & 1, lr = lane & 15, ls = lane >> 4;

#pragma unroll
    for (int mm=0;mm<4;++mm)
#pragma unroll
        for (int nn=0;nn<4;++nn)
#pragma unroll
            for (int r=0;r<4;++r) acc[mm][nn][r] = 0.f;

    const int nt = K >> 6;
    stage_tile(A, B, K, bm, bn, 0,  As,        Bs,        wv, lane);
    stage_tile(A, B, K, bm, bn, 64, As + 8192, Bs + 8192, wv, lane);

    for (int t = 0; t < nt; ++t) {
        const int cur = t & 1;
        bf16* AsC = As + cur * 8192;
        bf16* BsC = Bs + cur * 8192;

        if (t < nt - 1) asm volatile("s_waitcnt vmcnt(8)" ::: "memory");
        else            asm volatile("s_waitcnt vmcnt(0)" ::: "memory");
        __builtin_amdgcn_s_barrier();
        __builtin_amdgcn_sched_barrier(0);

        bf16x8 af[2][4], bfr[2][4];
#pragma unroll
        for (int ks=0; ks<2; ++ks) {
#pragma unroll
            for (int mm=0;mm<4;++mm) {
                int row = wr*64 + mm*16 + lr;
                af[ks][mm] = *(const bf16x8*)((char*)AsC + row*128 + (((ks*4+ls) ^ (row&7))<<4));
            }
#pragma unroll
            for (int nn=0;nn<4;++nn) {
                int row = wc*64 + nn*16 + lr;
                bfr[ks][nn] = *(const bf16x8*)((char*)BsC + row*128 + (((ks*4+ls) ^ (row&7))<<4));
            }
        }
        asm volatile("s_waitcnt lgkmcnt(0)" ::: "memory");
        __builtin_amdgcn_sched_barrier(0);
        __builtin_amdgcn_s_barrier();
        __builtin_amdgcn_sched_barrier(0);

        if (t + 2 < nt)
            stage_tile(A, B, K, bm, bn, (t+2) << 6, AsC, BsC, wv, lane);

        __builtin_amdgcn_s_setprio(1);
#pragma unroll
        for (int ks=0; ks<2; ++ks)
#pragma unroll
            for (int mm=0;mm<4;++mm)
#pragma unroll
                for (int nn=0;nn<4;++nn)
                    acc[mm][nn] = MFMA16(af[ks][mm], bfr[ks][nn], acc[mm][nn]);
        __builtin_amdgcn_s_setprio(0);
    }
}

__global__ __launch_bounds__(256) void gemm_o(const bf16* __restrict__ A, const bf16* __restrict__ B,
                                              float* __restrict__ Cp) {
    __shared__ __align__(16) bf16 As[2*128*64];
    __shared__ __align__(16) bf16 Bs[2*128*64];
    int flat = blockIdx.y * gridDim.x + blockIdx.x;
    int id = (flat & 7) * 64 + (flat >> 3);           // 512 = 8 * 64
    int bm = (id & 15) * 128, bn = (id >> 4) * 128;
    f32x4 acc[4][4];
    gemm_core(A, B, 4096, bm, bn, As, Bs, acc);

    const int lane = threadIdx.x & 63, wv = threadIdx.x >> 6;
    const int wr = wv >> 1, wc = wv & 1, lr = lane & 15, ls = lane >> 4;
#pragma unroll
    for (int mm=0;mm<4;++mm)
#pragma unroll
        for (int nn=0;nn<4;++nn)
#pragma unroll
            for (int r=0;r<4;++r) {
                int mg = bm + wr*64 + mm*16 + ls*4 + r;
                int ng = bn + wc*64 + nn*16 + lr;
                Cp[(size_t)mg * 4096 + ng] = acc[mm][nn][r];
            }
}

// ---------------------------------------------------------------------------
// Vt transpose (64x64 LDS tiles) + f32 cache emission + Wo bf16 conversion.
// ---------------------------------------------------------------------------
__global__ __launch_bounds__(256) void trans_cache_cvt(const bf16* __restrict__ QKVb, bf16* __restrict__ Vt,
                                                       float* __restrict__ cacheK, float* __restrict__ cacheV,
                                                       const float* __restrict__ Wo, bf16* __restrict__ Wob) {
    int b = blockIdx.x;
    if (b < 512) {
        __shared__ bf16 t[64][70];
        int dt = b & 15, st = b >> 4;
        int tt = threadIdx.x;
        int r = tt >> 2, c0 = (tt & 3) * 16;
#pragma unroll
        for (int i = 0; i < 2; ++i) {
            bf16x8 v = *(const bf16x8*)(QKVb + (size_t)(st*64 + r)*6144 + 5120 + dt*64 + c0 + i*8);
#pragma unroll
            for (int j = 0; j < 8; ++j) t[c0 + i*8 + j][r] = v[j];
        }
        __syncthreads();
        int c = tt >> 2, r0 = (tt & 3) * 16;
#pragma unroll
        for (int i = 0; i < 2; ++i) {
            bf16x8 v = *(const bf16x8*)(&t[c][r0 + i*8]);
            *(bf16x8*)(Vt + (size_t)(dt*64 + c)*2048 + st*64 + r0 + i*8) = v;
        }
    } else if (b < 2560) {
        int g = (b - 512) * 256 + threadIdx.x;
        int d8 = g & 15, s = (g >> 4) & 2047, j = (g >> 15) & 7, kv = g >> 18;
        int hk = j >> 2;
        bf16x8 v = *(const bf16x8*)(QKVb + (size_t)s*6144 + 4096 + kv*1024 + hk*128 + d8*8);
        float* dst = (kv ? cacheV : cacheK) + ((size_t)j*2048 + s)*128 + d8*8;
        float4 lo, hi;
        lo.x=(float)v[0]; lo.y=(float)v[1]; lo.z=(float)v[2]; lo.w=(float)v[3];
        hi.x=(float)v[4]; hi.y=(float)v[5]; hi.z=(float)v[6]; hi.w=(float)v[7];
        *(float4*)dst = lo;
        *(float4*)(dst + 4) = hi;
    } else {
        int i = (b - 2560) * 256 + threadIdx.x;
        if (i < 2097152) cvt8(Wo, Wob, i);
    }
}

// ---------------------------------------------------------------------------
// Flash attention (R14 proven): KVBLK=128, 16 iterations, 4 independent QK
// chains, setprio MFMA clusters, 128 KB double-buffered LDS, __expf softmax
// (fast v_exp path — exp2f libm wrapper measured -55us slower, R15).
// ---------------------------------------------------------------------------
__device__ __forceinline__ void stage_kv(const bf16* __restrict__ QKVb, const bf16* __restrict__ Vt,
                                         char* Ks, char* Vs, int kvh, int kt, int buf,
                                         int tid) {
#pragma unroll
    for (int i=0;i<4;++i) {                       // K tile [128 s][128 d] bf16, 32KB
        int off = i*8192 + tid*16;
        int row = off >> 8;
        int cg = (tid & 15) ^ (row & 7);
        gload16(QKVb + (size_t)(kt*128+row)*6144 + 4096 + kvh*128 + cg*8, Ks + buf*32768 + off);
    }
#pragma unroll
    for (int i=0;i<4;++i) {                       // V tile [128 d][128 s] bf16, 32KB
        int off = i*8192 + tid*16;
        int d = off >> 8;
        int cg = (tid & 15) ^ (d & 7);
        gload16(Vt + (size_t)(kvh*128+d)*2048 + kt*128 + cg*8, Vs + buf*32768 + off);
    }
}

__global__ __launch_bounds__(512) void flash_attn(const bf16* __restrict__ QKVb, const bf16* __restrict__ Vt,
                                                  bf16* __restrict__ AO) {
    __shared__ __align__(16) char Ks[2*32768];
    __shared__ __align__(16) char Vs[2*32768];
    const int tid = threadIdx.x, lane = tid & 63, wq = tid >> 6;
    const int l31 = lane & 31, hi = lane >> 5;
    const int h = blockIdx.y, kvh = h >> 2;
    const int q0w = blockIdx.x * 256 + wq * 32;

    bf16x8 qf[8];
#pragma unroll
    for (int f=0; f<8; ++f)
        qf[f] = *(const bf16x8*)(QKVb + (size_t)(q0w + l31)*6144 + h*128 + f*16 + hi*8);

    f32x16 acc[4];
#pragma unroll
    for (int db=0;db<4;++db)
#pragma unroll
        for (int r=0;r<16;++r) acc[db][r] = 0.f;
    float mrun = -1e30f, lrun = 0.f;

    stage_kv(QKVb, Vt, Ks, Vs, kvh, 0, 0, tid);
    __syncthreads();

    for (int t = 0; t < 16; ++t) {
        const int cur = t & 1;
        if (t + 1 < 16) stage_kv(QKVb, Vt, Ks, Vs, kvh, t+1, cur^1, tid);

        const char* KsB = Ks + cur*32768;
        f32x16 sc[4];
#pragma unroll
        for (int kc=0;kc<4;++kc)
#pragma unroll
            for (int r=0;r<16;++r) sc[kc][r] = 0.f;
        __builtin_amdgcn_s_setprio(1);
#pragma unroll
        for (int f=0; f<8; ++f) {
#pragma unroll
            for (int kc=0;kc<4;++kc) {
                int row = kc*32 + l31;
                bf16x8 kf = *(const bf16x8*)(KsB + row*256 + (((f*2+hi) ^ (row&7))<<4));
                sc[kc] = MFMA32(kf, qf[f], sc[kc]);
            }
        }
        __builtin_amdgcn_s_setprio(0);

        float tmax = sc[0][0];
#pragma unroll
        for (int kc=0;kc<4;++kc)
#pragma unroll
            for (int r=0;r<16;++r) tmax = fmaxf(tmax, sc[kc][r]);
        tmax = fmaxf(tmax, __shfl_xor(tmax, 32, 64));
        if (!__all(tmax <= mrun + 8.f)) {
            float mnew = fmaxf(mrun, tmax);
            float corr = __expf(mrun - mnew);
            mrun = mnew;
            lrun *= corr;
#pragma unroll
            for (int r=0;r<16;++r) {
                float cr = __shfl(corr, (r&3) + 8*(r>>2) + 4*hi, 64);
#pragma unroll
                for (int db=0;db<4;++db) acc[db][r] *= cr;
            }
        }
        float rs = 0.f;
#pragma unroll
        for (int kc=0;kc<4;++kc)
#pragma unroll
            for (int r=0;r<16;++r) { float e = __expf(sc[kc][r] - mrun); sc[kc][r] = e; rs += e; }
        rs += __shfl_xor(rs, 32, 64);
        lrun += rs;

        const char* VsB = Vs + cur*32768;
        __builtin_amdgcn_s_setprio(1);
#pragma unroll
        for (int kb=0;kb<8;++kb) {
            const int kc = kb>>1, r0 = (kb&1)*8;
            unsigned a0 = pk(sc[kc][r0+0], sc[kc][r0+1]);
            unsigned a1 = pk(sc[kc][r0+2], sc[kc][r0+3]);
            unsigned b0 = pk(sc[kc][r0+4], sc[kc][r0+5]);
            unsigned b1 = pk(sc[kc][r0+6], sc[kc][r0+7]);
            unsigned sa0 = (unsigned)__shfl_xor((int)a0, 32, 64);
            unsigned sa1 = (unsigned)__shfl_xor((int)a1, 32, 64);
            unsigned sb0 = (unsigned)__shfl_xor((int)b0, 32, 64);
            unsigned sb1 = (unsigned)__shfl_xor((int)b1, 32, 64);
            u32x4 w;
            w[0] = hi ? sb0 : a0;
            w[1] = hi ? sb1 : a1;
            w[2] = hi ? b0 : sa0;
            w[3] = hi ? b1 : sa1;
            bf16x8 pa = __builtin_bit_cast(bf16x8, w);
#pragma unroll
            for (int db=0;db<4;++db) {
                const int d = db*32 + l31;
                bf16x8 vf = *(const bf16x8*)(VsB + d*256 + (((kb*2+hi) ^ (d&7))<<4));
                acc[db] = MFMA32(pa, vf, acc[db]);
            }
        }
        __builtin_amdgcn_s_setprio(0);
        __syncthreads();
    }

    float linv = 1.0f / lrun;
#pragma unroll
    for (int r=0;r<16;++r) {
        int crw = (r&3) + 8*(r>>2) + 4*hi;
        float lv = __shfl(linv, crw, 64);
        size_t qrow = (size_t)q0w + crw;
#pragma unroll
        for (int db=0;db<4;++db)
            AO[qrow*4096 + h*128 + db*32 + l31] = (bf16)(acc[db][r] * lv);
    }
}

extern "C" void kernel_launch(void* const* d_in, const int* in_sizes, int n_in,
                              void* d_out, int out_size, void* d_ws, size_t ws_size,
                              hipStream_t stream) {
    const float* x  = (const float*)d_in[0];
    const float* Wq = (const float*)d_in[1];
    const float* Wk = (const float*)d_in[2];
    const float* Wv = (const float*)d_in[3];
    const float* Wo = (const float*)d_in[4];

    // ws layout (92.3 MB total, phase-disjoint aliasing):
    bf16* xb   = (bf16*)d_ws;                  // [2048,4096]; after gemm_qkv: first 2M elems = Vt
    bf16* QKVb = xb + (size_t)8388608;         // [2048,6144]
    bf16* Wqkv = QKVb + (size_t)12582912;      // [6144,4096]; after gemm_qkv:
                                               //   [0 : 16777216)  = Wo bf16
                                               //   [16777216 : end) = AO [2048,4096]
    bf16* Vt  = xb;
    bf16* Wob = Wqkv;
    bf16* AO  = Wqkv + (size_t)16777216;

    float* out = (float*)d_out;
    float* cacheK = out + (size_t)8388608;
    float* cacheV = cacheK + (size_t)2097152;

    const float qscale = 0.08838834764831845f;  // 1/sqrt(128)

    cvt_all<<<16384, 256, 0, stream>>>(x, Wq, Wk, Wv, xb, Wqkv);
    gemm_qkv<<<dim3(16, 32), 256, 0, stream>>>(xb, Wqkv, QKVb, qscale);
    trans_cache_cvt<<<10752, 256, 0, stream>>>(QKVb, Vt, cacheK, cacheV, Wo, Wob);
    flash_attn<<<dim3(8, 32), 512, 0, stream>>>(QKVb, Vt, AO);
    gemm_o<<<dim3(16, 32), 256, 0, stream>>>(AO, Wob, out);
}